// Round 3
// baseline (334.118 us; speedup 1.0000x reference)
//
#include <hip/hip_runtime.h>

// CRF forward (log-partition) — B=1024, T=512, K=64. One wave per batch.
// Exp-domain recurrence keeps exp/log OFF the serial chain:
//   u[i] = exp(alpha[i] - C);  step: u <- (E·u) * F,  F = exp(emit - 4.5)
// F is computed off-chain from prefetched emissions; C accumulates the 4.5
// bias and periodic rescale logs off-chain. Broadcast of u via LDS
// (no barrier needed: single wave, DS ops in-order) + packed-f32 FMAs.

constexpr int CRF_B = 1024;
constexpr int CRF_T = 512;
constexpr int CRF_K = 64;

typedef float v2f __attribute__((ext_vector_type(2)));

__device__ __forceinline__ float bcast_lane(float v, int lane) {
    return __int_as_float(__builtin_amdgcn_readlane(__float_as_int(v), lane));
}

__global__ __launch_bounds__(64) void crf_forward_kernel(
    const float* __restrict__ feats,      // [B, T, K]
    const float* __restrict__ trans,      // [K, K]
    const int*   __restrict__ seq_lens,   // [B]
    float*       __restrict__ out)        // [B]
{
    const int b    = blockIdx.x;
    const int lane = threadIdx.x;
    constexpr float G = 4.5f;             // per-step growth bias (baked into F)

    __shared__ __align__(16) float wbuf[2][CRF_K];

    // E[lane][j] = exp(trans[lane][j]) as 32 packed f32 pairs (static -> VGPRs).
    v2f Epk[CRF_K / 2];
    {
        const float4* trow = (const float4*)(trans + lane * CRF_K);
#pragma unroll
        for (int q = 0; q < CRF_K / 4; ++q) {
            const float4 t4 = trow[q];
            Epk[2 * q + 0] = v2f{__expf(t4.x), __expf(t4.y)};
            Epk[2 * q + 1] = v2f{__expf(t4.z), __expf(t4.w)};
        }
    }

    const int L   = seq_lens[b];          // uniform across the wave
    const int Lm1 = L - 1;
    const float* fb = feats + (size_t)b * CRF_T * CRF_K + lane;

    // t = 0 init (exp domain).
    const float fv0 = fb[0];
    const float m0  = bcast_lane(fv0, 0);
    float u = __expf(fv0 - m0);
    float C = m0;

    // Emission prefetch: p2 = emit[t+1], p3 = emit[t+2] at loop top.
    float p2 = fb[(size_t)min(2, Lm1) * CRF_K];
    float p3 = fb[(size_t)min(3, Lm1) * CRF_K];
    float Fc = __expf(fb[(size_t)min(1, Lm1) * CRF_K] - G);   // factor for t=1

    int p = 0;
    for (int t = 1; t < L; ++t) {
        const float Fn = __expf(p2 - G);  // factor for t+1 — off the u-chain
        p2 = p3;
        p3 = fb[(size_t)min(t + 3, Lm1) * CRF_K];   // prefetch t+3 (clamped)

        wbuf[p][lane] = u;                // ds_write; in-order with reads below
        const float4* src = (const float4*)wbuf[p];

        v2f acc[8];
#pragma unroll
        for (int k = 0; k < 8; ++k) acc[k] = v2f{0.f, 0.f};
#pragma unroll
        for (int q = 0; q < 16; ++q) {    // 16 broadcast b128 reads, 32 pk_fma
            const float4 w4 = src[q];
            const v2f wlo = v2f{w4.x, w4.y};
            const v2f whi = v2f{w4.z, w4.w};
            acc[(2 * q) & 7]     = __builtin_elementwise_fma(Epk[2 * q],     wlo, acc[(2 * q) & 7]);
            acc[(2 * q + 1) & 7] = __builtin_elementwise_fma(Epk[2 * q + 1], whi, acc[(2 * q + 1) & 7]);
        }
        const v2f a = ((acc[0] + acc[1]) + (acc[2] + acc[3]))
                    + ((acc[4] + acc[5]) + (acc[6] + acc[7]));
        u = (a.x + a.y) * Fc;

        if ((t & 7) == 0) {               // periodic rescale (~25 cy / 8 steps)
            const float m = bcast_lane(u, 0);
            const float r = __builtin_amdgcn_rcpf(m);
            u *= r;
            C += __logf(m);               // off-chain: only feeds final C
        }
        Fc = Fn;
        p ^= 1;
    }

    C += G * (float)Lm1;                  // restore the baked bias

    // Final LSE over lanes: out = C + log(sum_i u[i]).
    float e = u;
#pragma unroll
    for (int off = 32; off > 0; off >>= 1) e += __shfl_xor(e, off, 64);
    if (lane == 0) out[b] = C + __logf(e);
}

extern "C" void kernel_launch(void* const* d_in, const int* in_sizes, int n_in,
                              void* d_out, int out_size, void* d_ws, size_t ws_size,
                              hipStream_t stream)
{
    const float* feats    = (const float*)d_in[0];
    const float* trans    = (const float*)d_in[1];
    const int*   seq_lens = (const int*)d_in[2];
    float*       out      = (float*)d_out;

    crf_forward_kernel<<<dim3(CRF_B), dim3(CRF_K), 0, stream>>>(
        feats, trans, seq_lens, out);
}

// Round 4
// 141.807 us; speedup vs baseline: 2.3561x; 2.3561x over previous
//
#include <hip/hip_runtime.h>

// CRF forward (log-partition) — B=1024, T=512, K=64. One wave per batch.
// Exp-domain recurrence keeps exp/log OFF the serial chain:
//   u[i] = exp(alpha[i] - C);  step: u <- (E·u) * F,  F = exp(emit - 4.5)
// Broadcast of u via LDS (single wave -> no barrier; DS ops are in-order).
// Key fixes this round:
//   * __launch_bounds__(64, 1): we need only 1 wave/SIMD, so give the
//     allocator the full VGPR budget -> E[64] and wreg[16] stay resident
//     (R2/R3 had VGPR_Count=52 => E was spilled to scratch, reloaded
//     64 dwords/step on the critical chain).
//   * Batched ds_read: all 16 float4 loads into registers, sched_barrier(0),
//     then the FMA block -> one lgkmcnt wait instead of 16 serialized ones.

constexpr int CRF_B = 1024;
constexpr int CRF_T = 512;
constexpr int CRF_K = 64;

typedef float v2f __attribute__((ext_vector_type(2)));

__device__ __forceinline__ float bcast_lane(float v, int lane) {
    return __int_as_float(__builtin_amdgcn_readlane(__float_as_int(v), lane));
}

__global__ __launch_bounds__(64, 1) void crf_forward_kernel(
    const float* __restrict__ feats,      // [B, T, K]
    const float* __restrict__ trans,      // [K, K]
    const int*   __restrict__ seq_lens,   // [B]
    float*       __restrict__ out)        // [B]
{
    const int b    = blockIdx.x;
    const int lane = threadIdx.x;
    constexpr float G = 4.5f;             // per-step growth bias (baked into F)

    __shared__ __align__(16) float wbuf[2][CRF_K];

    // E[lane][j] = exp(trans[lane][j]) as 32 packed f32 pairs (static -> VGPRs).
    v2f Epk[CRF_K / 2];
    {
        const float4* trow = (const float4*)(trans + lane * CRF_K);
#pragma unroll
        for (int q = 0; q < CRF_K / 4; ++q) {
            const float4 t4 = trow[q];
            Epk[2 * q + 0] = v2f{__expf(t4.x), __expf(t4.y)};
            Epk[2 * q + 1] = v2f{__expf(t4.z), __expf(t4.w)};
        }
    }

    const int L   = seq_lens[b];          // uniform across the wave
    const int Lm1 = L - 1;
    const float* fb = feats + (size_t)b * CRF_T * CRF_K + lane;

    // t = 0 init (exp domain).
    const float fv0 = fb[0];
    const float m0  = bcast_lane(fv0, 0);
    float u = __expf(fv0 - m0);
    float C = m0;

    // Emission prefetch: p2 = emit[t+1], p3 = emit[t+2] at loop top.
    float p2 = fb[(size_t)min(2, Lm1) * CRF_K];
    float p3 = fb[(size_t)min(3, Lm1) * CRF_K];
    float Fc = __expf(fb[(size_t)min(1, Lm1) * CRF_K] - G);   // factor for t=1

    int p = 0;
    for (int t = 1; t < L; ++t) {
        const float Fn = __expf(p2 - G);  // factor for t+1 — off the u-chain
        p2 = p3;
        p3 = fb[(size_t)min(t + 3, Lm1) * CRF_K];   // prefetch t+3 (clamped)

        wbuf[p][lane] = u;                // ds_write; in-order with reads below
        const float4* src = (const float4*)wbuf[p];

        // --- batched broadcast reads: 16x ds_read_b128 -> registers ---
        float4 wreg[16];
#pragma unroll
        for (int q = 0; q < 16; ++q) wreg[q] = src[q];
        __builtin_amdgcn_sched_barrier(0);   // keep loads clustered before FMAs

        // --- 32 packed FMAs on 8 independent accumulator chains ---
        v2f acc[8];
#pragma unroll
        for (int k = 0; k < 8; ++k) acc[k] = v2f{0.f, 0.f};
#pragma unroll
        for (int q = 0; q < 16; ++q) {
            const v2f wlo = v2f{wreg[q].x, wreg[q].y};
            const v2f whi = v2f{wreg[q].z, wreg[q].w};
            acc[(2 * q) & 7]     = __builtin_elementwise_fma(Epk[2 * q],     wlo, acc[(2 * q) & 7]);
            acc[(2 * q + 1) & 7] = __builtin_elementwise_fma(Epk[2 * q + 1], whi, acc[(2 * q + 1) & 7]);
        }
        const v2f a = ((acc[0] + acc[1]) + (acc[2] + acc[3]))
                    + ((acc[4] + acc[5]) + (acc[6] + acc[7]));
        u = (a.x + a.y) * Fc;

        if ((t & 7) == 0) {               // periodic rescale; log is off-chain
            const float m = bcast_lane(u, 0);
            const float r = __builtin_amdgcn_rcpf(m);
            u *= r;
            C += __logf(m);
        }
        Fc = Fn;
        p ^= 1;
    }

    C += G * (float)Lm1;                  // restore the baked bias

    // Final LSE over lanes: out = C + log(sum_i u[i]).
    float e = u;
#pragma unroll
    for (int off = 32; off > 0; off >>= 1) e += __shfl_xor(e, off, 64);
    if (lane == 0) out[b] = C + __logf(e);
}

extern "C" void kernel_launch(void* const* d_in, const int* in_sizes, int n_in,
                              void* d_out, int out_size, void* d_ws, size_t ws_size,
                              hipStream_t stream)
{
    const float* feats    = (const float*)d_in[0];
    const float* trans    = (const float*)d_in[1];
    const int*   seq_lens = (const int*)d_in[2];
    float*       out      = (float*)d_out;

    crf_forward_kernel<<<dim3(CRF_B), dim3(CRF_K), 0, stream>>>(
        feats, trans, seq_lens, out);
}